// Round 3
// baseline (53.664 us; speedup 1.0000x reference)
//
#include <hip/hip_runtime.h>

#define NJ 32
#define BLK 64
#define GRAVZ 9.81f

struct V3 { float x, y, z; };

__device__ __forceinline__ V3 mkv3(float x, float y, float z){ V3 r; r.x=x; r.y=y; r.z=z; return r; }
__device__ __forceinline__ V3 vadd(V3 a, V3 b){ return mkv3(a.x+b.x, a.y+b.y, a.z+b.z); }
__device__ __forceinline__ V3 vsub(V3 a, V3 b){ return mkv3(a.x-b.x, a.y-b.y, a.z-b.z); }
__device__ __forceinline__ V3 vscl(float s, V3 a){ return mkv3(s*a.x, s*a.y, s*a.z); }
__device__ __forceinline__ V3 vcross(V3 a, V3 b){
    return mkv3(a.y*b.z - a.z*b.y, a.z*b.x - a.x*b.z, a.x*b.y - a.y*b.x);
}
// Rt*v with R=rot_z(q): Rt = [[c,s,0],[-s,c,0],[0,0,1]]
__device__ __forceinline__ V3 rtv(float c, float s, V3 v){ return mkv3(c*v.x + s*v.y, c*v.y - s*v.x, v.z); }
// R*v
__device__ __forceinline__ V3 rv (float c, float s, V3 v){ return mkv3(c*v.x - s*v.y, s*v.x + c*v.y, v.z); }

// Per-joint uniform precompute: Ibar (9) + m*com (3) -> ws[12*j ..]
__global__ void precomp_kernel(const float* __restrict__ mass,
                               const float* __restrict__ com,
                               const float* __restrict__ inertia,
                               float* __restrict__ ws)
{
    int j = threadIdx.x;
    if (j >= NJ) return;
    float m  = mass[j];
    float cx = com[3*j+0], cy = com[3*j+1], cz = com[3*j+2];
    float cc = cx*cx + cy*cy + cz*cz;
    const float* I = inertia + 9*j;
    float* o = ws + 12*j;
    o[0] = I[0] + m*(cc - cx*cx);
    o[1] = I[1] - m*(cx*cy);
    o[2] = I[2] - m*(cx*cz);
    o[3] = I[3] - m*(cy*cx);
    o[4] = I[4] + m*(cc - cy*cy);
    o[5] = I[5] - m*(cy*cz);
    o[6] = I[6] - m*(cz*cx);
    o[7] = I[7] - m*(cz*cy);
    o[8] = I[8] + m*(cc - cz*cz);
    o[9]  = m*cx;
    o[10] = m*cy;
    o[11] = m*cz;
}

__global__ __launch_bounds__(BLK) void rnea_kernel(
    const float* __restrict__ q,
    const float* __restrict__ qd,
    const float* __restrict__ qdd,
    const float* __restrict__ trans,
    const float* __restrict__ mass,
    const float* __restrict__ damping,
    const float* __restrict__ pre,   // 12 floats per joint: Ibar row-major, then m*com
    float* __restrict__ out,
    int Bn)
{
    // Per-thread trajectory columns; [j*BLK + tid] -> consecutive lanes,
    // consecutive banks (2 lanes/bank = free). No cross-thread use, no barriers.
    __shared__ float lC  [NJ*BLK];
    __shared__ float lS  [NJ*BLK];
    __shared__ float lQd [NJ*BLK];
    __shared__ float lQdd[NJ*BLK];

    int tid = threadIdx.x;
    int b = blockIdx.x * BLK + tid;
    if (b >= Bn) return;
    size_t base = (size_t)b * NJ;

    V3 vl = mkv3(0,0,0), va = mkv3(0,0,0), al = mkv3(0,0,GRAVZ), aa = mkv3(0,0,0);

    // ---- Forward scan: small loop body (I$-resident), depth-2 global prefetch.
    float qa  = q  [base+0], qda  = qd[base+0], qdda  = qdd[base+0];
    float qb  = q  [base+1], qdb  = qd[base+1], qddb  = qdd[base+1];
    #pragma unroll 1
    for (int j = 0; j < NJ; ++j) {
        float qj = qa, qdj = qda, qddj = qdda;
        qa = qb; qda = qdb; qdda = qddb;
        if (j + 2 < NJ) {
            qb = q[base+j+2]; qdb = qd[base+j+2]; qddb = qdd[base+j+2];
        }
        float s, c;
        __sincosf(qj, &s, &c);
        int li = j*BLK + tid;
        lC[li] = c; lS[li] = s; lQd[li] = qdj; lQdd[li] = qddj;

        V3 p  = mkv3(trans[3*j+0], trans[3*j+1], trans[3*j+2]);   // uniform -> s_load
        V3 t  = vscl(-1.f, rtv(c, s, p));
        V3 wv = rtv(c, s, va);
        V3 lv = vadd(vcross(t, wv), rtv(c, s, vl));
        V3 wa = rtv(c, s, aa);
        V3 la = vadd(vcross(t, wa), rtv(c, s, al));
        va = mkv3(wv.x, wv.y, wv.z + qdj);
        vl = lv;
        aa = mkv3(wa.x + va.y*qdj, wa.y - va.x*qdj, wa.z + qddj);
        al = mkv3(la.x + vl.y*qdj, la.y - vl.x*qdj, la.z);
    }

    // ---- Backward scan with exact state inversion; depth-1 LDS prefetch.
    V3 gl = mkv3(0,0,0), ga = mkv3(0,0,0);
    {
        int li = (NJ-1)*BLK + tid;
        float cN = lC[li], sN = lS[li], qdN = lQd[li], qddN = lQdd[li];

        #pragma unroll 1
        for (int j = NJ-1; j >= 0; --j) {
            float c = cN, s = sN, qdj = qdN, qddj = qddN;
            if (j > 0) {
                int lp = (j-1)*BLK + tid;
                cN = lC[lp]; sN = lS[lp]; qdN = lQd[lp]; qddN = lQdd[lp];
            }

            float m = mass[j];                   // uniform -> s_load
            const float* w = pre + 12*j;         // uniform -> s_load
            float I00=w[0], I01=w[1], I02=w[2];
            float I10=w[3], I11=w[4], I12=w[5];
            float I20=w[6], I21=w[7], I22=w[8];
            V3 mc = mkv3(w[9], w[10], w[11]);

            V3 fa_l = vadd(vscl(m, al), vcross(mc, aa));
            V3 Iaa = mkv3(I00*aa.x + I01*aa.y + I02*aa.z,
                          I10*aa.x + I11*aa.y + I12*aa.z,
                          I20*aa.x + I21*aa.y + I22*aa.z);
            V3 fa_a = vadd(Iaa, vcross(mc, al));
            V3 fv_l = vadd(vscl(m, vl), vcross(mc, va));
            V3 Iva = mkv3(I00*va.x + I01*va.y + I02*va.z,
                          I10*va.x + I11*va.y + I12*va.z,
                          I20*va.x + I21*va.y + I22*va.z);
            V3 fv_a = vadd(Iva, vcross(mc, vl));
            V3 cf_a = vadd(vcross(va, fv_a), vcross(vl, fv_l));
            V3 cf_l = vcross(va, fv_l);
            V3 f_l = vadd(vadd(fa_l, cf_l), gl);
            V3 f_a = vadd(vadd(fa_a, cf_a), ga);

            out[base + j] = f_a.z + damping[j] * qdj;

            V3 p = mkv3(trans[3*j+0], trans[3*j+1], trans[3*j+2]);
            V3 Rf = rv(c, s, f_l);
            gl = Rf;
            ga = vadd(vcross(p, Rf), rv(c, s, f_a));

            if (j > 0) {
                // Invert the forward step: recover state after joint j-1.
                V3 wv = mkv3(va.x, va.y, va.z - qdj);
                V3 wa = mkv3(aa.x - va.y*qdj, aa.y + va.x*qdj, aa.z - qddj);
                V3 la = mkv3(al.x - vl.y*qdj, al.y + vl.x*qdj, al.z);
                V3 t  = vscl(-1.f, rtv(c, s, p));
                V3 vlp = rv(c, s, vsub(vl, vcross(t, wv)));
                V3 alp = rv(c, s, vsub(la, vcross(t, wa)));
                va = rv(c, s, wv);
                aa = rv(c, s, wa);
                vl = vlp;
                al = alp;
            }
        }
    }
}

extern "C" void kernel_launch(void* const* d_in, const int* in_sizes, int n_in,
                              void* d_out, int out_size, void* d_ws, size_t ws_size,
                              hipStream_t stream) {
    const float* q       = (const float*)d_in[0];
    const float* qd      = (const float*)d_in[1];
    const float* qdd     = (const float*)d_in[2];
    const float* trans   = (const float*)d_in[3];
    const float* mass    = (const float*)d_in[4];
    const float* com     = (const float*)d_in[5];
    const float* inertia = (const float*)d_in[6];
    const float* damping = (const float*)d_in[7];
    float* out = (float*)d_out;
    float* pre = (float*)d_ws;   // 32*12 floats = 1536 B

    hipLaunchKernelGGL(precomp_kernel, dim3(1), dim3(64), 0, stream,
                       mass, com, inertia, pre);

    int Bn = in_sizes[0] / NJ;
    int grid = (Bn + BLK - 1) / BLK;
    hipLaunchKernelGGL(rnea_kernel, dim3(grid), dim3(BLK), 0, stream,
                       q, qd, qdd, trans, mass, damping, pre, out, Bn);
}

// Round 4
// 29.473 us; speedup vs baseline: 1.8208x; 1.8208x over previous
//
#include <hip/hip_runtime.h>

#define NJ 32
#define BLK 64
#define LSTR 65          // LDS stride padding: bank = (j+t)%32 -> worst 2-way = free
#define GRAVZ 9.81f

struct V3 { float x, y, z; };

__device__ __forceinline__ V3 mkv3(float x, float y, float z){ V3 r; r.x=x; r.y=y; r.z=z; return r; }
__device__ __forceinline__ V3 vadd(V3 a, V3 b){ return mkv3(a.x+b.x, a.y+b.y, a.z+b.z); }
__device__ __forceinline__ V3 vsub(V3 a, V3 b){ return mkv3(a.x-b.x, a.y-b.y, a.z-b.z); }
__device__ __forceinline__ V3 vscl(float s, V3 a){ return mkv3(s*a.x, s*a.y, s*a.z); }
__device__ __forceinline__ V3 vcross(V3 a, V3 b){
    return mkv3(a.y*b.z - a.z*b.y, a.z*b.x - a.x*b.z, a.x*b.y - a.y*b.x);
}
// Rt*v with R=rot_z(q): Rt = [[c,s,0],[-s,c,0],[0,0,1]]
__device__ __forceinline__ V3 rtv(float c, float s, V3 v){ return mkv3(c*v.x + s*v.y, c*v.y - s*v.x, v.z); }
// R*v
__device__ __forceinline__ V3 rv (float c, float s, V3 v){ return mkv3(c*v.x - s*v.y, s*v.x + c*v.y, v.z); }

// Per-joint uniform precompute: Ibar (9) + m*com (3) -> ws[12*j ..]
__global__ void precomp_kernel(const float* __restrict__ mass,
                               const float* __restrict__ com,
                               const float* __restrict__ inertia,
                               float* __restrict__ ws)
{
    int j = threadIdx.x;
    if (j >= NJ) return;
    float m  = mass[j];
    float cx = com[3*j+0], cy = com[3*j+1], cz = com[3*j+2];
    float cc = cx*cx + cy*cy + cz*cz;
    const float* I = inertia + 9*j;
    float* o = ws + 12*j;
    o[0] = I[0] + m*(cc - cx*cx);
    o[1] = I[1] - m*(cx*cy);
    o[2] = I[2] - m*(cx*cz);
    o[3] = I[3] - m*(cy*cx);
    o[4] = I[4] + m*(cc - cy*cy);
    o[5] = I[5] - m*(cy*cz);
    o[6] = I[6] - m*(cz*cx);
    o[7] = I[7] - m*(cz*cy);
    o[8] = I[8] + m*(cc - cz*cz);
    o[9]  = m*cx;
    o[10] = m*cy;
    o[11] = m*cz;
}

__global__ __launch_bounds__(BLK) void rnea_kernel(
    const float* __restrict__ q,
    const float* __restrict__ qd,
    const float* __restrict__ qdd,
    const float* __restrict__ trans,
    const float* __restrict__ mass,
    const float* __restrict__ damping,
    const float* __restrict__ pre,   // 12 floats/joint: Ibar row-major, then m*com
    float* __restrict__ out,
    int Bn)
{
    // Transposed per-joint trajectories: lX[j*LSTR + row], row = thread's row.
    __shared__ float lC  [NJ*LSTR];
    __shared__ float lS  [NJ*LSTR];
    __shared__ float lQd [NJ*LSTR];
    __shared__ float lQdd[NJ*LSTR];   // overwritten with tau during backward

    const int tid = threadIdx.x;
    const size_t blk4 = (size_t)blockIdx.x * (BLK * NJ / 4);   // float4 tile base
    const size_t maxIdx4 = ((size_t)Bn * NJ) / 4 - 1;

    // ---- Stage: coalesced float4 loads, elementwise sincos, transposed LDS write.
    const float4* q4   = reinterpret_cast<const float4*>(q);
    const float4* qd4  = reinterpret_cast<const float4*>(qd);
    const float4* qdd4 = reinterpret_cast<const float4*>(qdd);
    #pragma unroll
    for (int i = 0; i < NJ/4; ++i) {                // 8 iters: 512 float4 per block
        int lin = i*BLK + tid;                      // float4 index in tile
        size_t g = blk4 + lin; if (g > maxIdx4) g = maxIdx4;
        int row  = lin >> 3;                        // 8 float4 per 32-joint row
        int col4 = (lin & 7) * 4;                   // starting joint index
        float4 vq  = q4[g];
        float4 vd  = qd4[g];
        float4 vdd = qdd4[g];
        float s0,c0,s1,c1,s2,c2,s3,c3;
        __sincosf(vq.x,&s0,&c0); __sincosf(vq.y,&s1,&c1);
        __sincosf(vq.z,&s2,&c2); __sincosf(vq.w,&s3,&c3);
        lC[(col4+0)*LSTR+row]=c0; lS[(col4+0)*LSTR+row]=s0;
        lC[(col4+1)*LSTR+row]=c1; lS[(col4+1)*LSTR+row]=s1;
        lC[(col4+2)*LSTR+row]=c2; lS[(col4+2)*LSTR+row]=s2;
        lC[(col4+3)*LSTR+row]=c3; lS[(col4+3)*LSTR+row]=s3;
        lQd[(col4+0)*LSTR+row]=vd.x;  lQd[(col4+1)*LSTR+row]=vd.y;
        lQd[(col4+2)*LSTR+row]=vd.z;  lQd[(col4+3)*LSTR+row]=vd.w;
        lQdd[(col4+0)*LSTR+row]=vdd.x; lQdd[(col4+1)*LSTR+row]=vdd.y;
        lQdd[(col4+2)*LSTR+row]=vdd.z; lQdd[(col4+3)*LSTR+row]=vdd.w;
    }
    __syncthreads();

    V3 vl = mkv3(0,0,0), va = mkv3(0,0,0), al = mkv3(0,0,GRAVZ), aa = mkv3(0,0,0);

    // ---- Forward scan (fully unrolled; static LDS offsets; compiler schedules).
    #pragma unroll
    for (int j = 0; j < NJ; ++j) {
        float c = lC[j*LSTR+tid], s = lS[j*LSTR+tid];
        float qdj = lQd[j*LSTR+tid], qddj = lQdd[j*LSTR+tid];
        V3 p  = mkv3(trans[3*j+0], trans[3*j+1], trans[3*j+2]);   // uniform -> s_load
        V3 t  = vscl(-1.f, rtv(c, s, p));
        V3 wv = rtv(c, s, va);
        V3 lv = vadd(vcross(t, wv), rtv(c, s, vl));
        V3 wa = rtv(c, s, aa);
        V3 la = vadd(vcross(t, wa), rtv(c, s, al));
        va = mkv3(wv.x, wv.y, wv.z + qdj);
        vl = lv;
        aa = mkv3(wa.x + va.y*qdj, wa.y - va.x*qdj, wa.z + qddj);
        al = mkv3(la.x + vl.y*qdj, la.y - vl.x*qdj, la.z);
    }

    // ---- Backward scan with exact state inversion (fully unrolled).
    V3 gl = mkv3(0,0,0), ga = mkv3(0,0,0);
    #pragma unroll
    for (int j = NJ-1; j >= 0; --j) {
        float c = lC[j*LSTR+tid], s = lS[j*LSTR+tid];
        float qdj = lQd[j*LSTR+tid], qddj = lQdd[j*LSTR+tid];

        float m = mass[j];                   // uniform -> s_load
        const float* w = pre + 12*j;         // uniform -> s_load
        float I00=w[0], I01=w[1], I02=w[2];
        float I10=w[3], I11=w[4], I12=w[5];
        float I20=w[6], I21=w[7], I22=w[8];
        V3 mc = mkv3(w[9], w[10], w[11]);

        V3 fa_l = vadd(vscl(m, al), vcross(mc, aa));
        V3 Iaa = mkv3(I00*aa.x + I01*aa.y + I02*aa.z,
                      I10*aa.x + I11*aa.y + I12*aa.z,
                      I20*aa.x + I21*aa.y + I22*aa.z);
        V3 fa_a = vadd(Iaa, vcross(mc, al));
        V3 fv_l = vadd(vscl(m, vl), vcross(mc, va));
        V3 Iva = mkv3(I00*va.x + I01*va.y + I02*va.z,
                      I10*va.x + I11*va.y + I12*va.z,
                      I20*va.x + I21*va.y + I22*va.z);
        V3 fv_a = vadd(Iva, vcross(mc, vl));
        V3 cf_a = vadd(vcross(va, fv_a), vcross(vl, fv_l));
        V3 cf_l = vcross(va, fv_l);
        V3 f_l = vadd(vadd(fa_l, cf_l), gl);
        V3 f_a = vadd(vadd(fa_a, cf_a), ga);

        // tau -> dead lQdd slot (qddj already in register); coalesced store later.
        lQdd[j*LSTR+tid] = f_a.z + damping[j]*qdj;

        V3 p = mkv3(trans[3*j+0], trans[3*j+1], trans[3*j+2]);
        V3 Rf = rv(c, s, f_l);
        gl = Rf;
        ga = vadd(vcross(p, Rf), rv(c, s, f_a));

        if (j > 0) {
            // Invert the forward step: recover state after joint j-1.
            V3 wv = mkv3(va.x, va.y, va.z - qdj);
            V3 wa = mkv3(aa.x - va.y*qdj, aa.y + va.x*qdj, aa.z - qddj);
            V3 la = mkv3(al.x - vl.y*qdj, al.y + vl.x*qdj, al.z);
            V3 t  = vscl(-1.f, rtv(c, s, p));
            V3 vlp = rv(c, s, vsub(vl, vcross(t, wv)));
            V3 alp = rv(c, s, vsub(la, vcross(t, wa)));
            va = rv(c, s, wv);
            aa = rv(c, s, wa);
            vl = vlp;
            al = alp;
        }
    }
    __syncthreads();

    // ---- Transposed coalesced float4 output store.
    float4* o4 = reinterpret_cast<float4*>(out);
    #pragma unroll
    for (int i = 0; i < NJ/4; ++i) {
        int lin = i*BLK + tid;
        size_t g = blk4 + lin;
        if (g <= maxIdx4) {
            int row  = lin >> 3;
            int col4 = (lin & 7) * 4;
            float4 v;
            v.x = lQdd[(col4+0)*LSTR+row];
            v.y = lQdd[(col4+1)*LSTR+row];
            v.z = lQdd[(col4+2)*LSTR+row];
            v.w = lQdd[(col4+3)*LSTR+row];
            o4[g] = v;
        }
    }
}

extern "C" void kernel_launch(void* const* d_in, const int* in_sizes, int n_in,
                              void* d_out, int out_size, void* d_ws, size_t ws_size,
                              hipStream_t stream) {
    const float* q       = (const float*)d_in[0];
    const float* qd      = (const float*)d_in[1];
    const float* qdd     = (const float*)d_in[2];
    const float* trans   = (const float*)d_in[3];
    const float* mass    = (const float*)d_in[4];
    const float* com     = (const float*)d_in[5];
    const float* inertia = (const float*)d_in[6];
    const float* damping = (const float*)d_in[7];
    float* out = (float*)d_out;
    float* pre = (float*)d_ws;   // 32*12 floats = 1536 B

    hipLaunchKernelGGL(precomp_kernel, dim3(1), dim3(64), 0, stream,
                       mass, com, inertia, pre);

    int Bn = in_sizes[0] / NJ;
    int grid = (Bn + BLK - 1) / BLK;
    hipLaunchKernelGGL(rnea_kernel, dim3(grid), dim3(BLK), 0, stream,
                       q, qd, qdd, trans, mass, damping, pre, out, Bn);
}

// Round 5
// 24.197 us; speedup vs baseline: 2.2178x; 1.2180x over previous
//
#include <hip/hip_runtime.h>

#define NJ 32
#define BLK 64
#define LSTR 65          // LDS stride padding: worst-case 2-way banks = free
#define GRAVZ 9.81f

// Per-joint uniform precompute -> ws[12*j ..]:
// [0..2] m*com  [3..5] Ibar col2  [6] m  [7] m*G  [8..10] p  [11] damping
__global__ void precomp_kernel(const float* __restrict__ mass,
                               const float* __restrict__ com,
                               const float* __restrict__ inertia,
                               const float* __restrict__ trans,
                               const float* __restrict__ damping,
                               float* __restrict__ ws)
{
    int j = threadIdx.x;
    if (j >= NJ) return;
    float m  = mass[j];
    float cx = com[3*j+0], cy = com[3*j+1], cz = com[3*j+2];
    float cc = cx*cx + cy*cy + cz*cz;
    const float* I = inertia + 9*j;
    float* o = ws + 12*j;
    o[0] = m*cx;  o[1] = m*cy;  o[2] = m*cz;
    // Ibar = I + m*(cc*Id - c c^T); col 2:
    o[3] = I[2] - m*(cx*cz);
    o[4] = I[5] - m*(cy*cz);
    o[5] = I[8] + m*(cc - cz*cz);
    o[6] = m;  o[7] = m*GRAVZ;
    o[8] = trans[3*j+0];  o[9] = trans[3*j+1];  o[10] = trans[3*j+2];
    o[11] = damping[j];
}

__global__ __launch_bounds__(BLK) void rnea_kernel(
    const float* __restrict__ q,
    const float* __restrict__ qd,
    const float* __restrict__ qdd,
    const float* __restrict__ pre,
    float* __restrict__ out,
    int Bn)
{
    // Transposed per-joint trajectories: lX[j*LSTR + row].
    // lC/lS hold (cos q, sin q) after stage; overwritten with (cos phi, sin phi)
    // by the forward scan. lQdd's slots are overwritten with tau in backward.
    __shared__ float lC  [NJ*LSTR];
    __shared__ float lS  [NJ*LSTR];
    __shared__ float lQd [NJ*LSTR];
    __shared__ float lQdd[NJ*LSTR];

    const int tid = threadIdx.x;
    const size_t blk4 = (size_t)blockIdx.x * (BLK * NJ / 4);
    const size_t maxIdx4 = ((size_t)Bn * NJ) / 4 - 1;

    // ---- Stage: coalesced float4 loads, elementwise sincos, transposed LDS write.
    const float4* q4   = reinterpret_cast<const float4*>(q);
    const float4* qd4  = reinterpret_cast<const float4*>(qd);
    const float4* qdd4 = reinterpret_cast<const float4*>(qdd);
    #pragma unroll
    for (int i = 0; i < NJ/4; ++i) {
        int lin = i*BLK + tid;
        size_t g = blk4 + lin; if (g > maxIdx4) g = maxIdx4;
        int row  = lin >> 3;
        int col4 = (lin & 7) * 4;
        float4 vq  = q4[g];
        float4 vd  = qd4[g];
        float4 vdd = qdd4[g];
        float s0,c0,s1,c1,s2,c2,s3,c3;
        __sincosf(vq.x,&s0,&c0); __sincosf(vq.y,&s1,&c1);
        __sincosf(vq.z,&s2,&c2); __sincosf(vq.w,&s3,&c3);
        lC[(col4+0)*LSTR+row]=c0; lS[(col4+0)*LSTR+row]=s0;
        lC[(col4+1)*LSTR+row]=c1; lS[(col4+1)*LSTR+row]=s1;
        lC[(col4+2)*LSTR+row]=c2; lS[(col4+2)*LSTR+row]=s2;
        lC[(col4+3)*LSTR+row]=c3; lS[(col4+3)*LSTR+row]=s3;
        lQd[(col4+0)*LSTR+row]=vd.x;  lQd[(col4+1)*LSTR+row]=vd.y;
        lQd[(col4+2)*LSTR+row]=vd.z;  lQd[(col4+3)*LSTR+row]=vd.w;
        lQdd[(col4+0)*LSTR+row]=vdd.x; lQdd[(col4+1)*LSTR+row]=vdd.y;
        lQdd[(col4+2)*LSTR+row]=vdd.z; lQdd[(col4+3)*LSTR+row]=vdd.w;
    }
    __syncthreads();

    // ---- Forward scan, world frame.
    // State: w = sum(qd), alpha = sum(qdd); VL=(VLx,VLy,0); AL=(ALx,ALy,G).
    float cp = 1.f, sp = 0.f;        // cos/sin of phi_{j-1}
    float w = 0.f, alpha = 0.f;
    float VLx = 0.f, VLy = 0.f, ALx = 0.f, ALy = 0.f;

    #pragma unroll
    for (int j = 0; j < NJ; ++j) {
        float cq = lC[j*LSTR+tid], sq = lS[j*LSTR+tid];
        float qdj = lQd[j*LSTR+tid], qddj = lQdd[j*LSTR+tid];
        float px = pre[12*j+8], py = pre[12*j+9];      // uniform -> s_load
        // d_j = Rz(phi_{j-1}) p (z comp unused in fwd)
        float dx = cp*px - sp*py;
        float dy = sp*px + cp*py;
        // VL_j = VL_{j-1} + w_{j-1} * (-dy, dx)
        VLx = fmaf(-w, dy, VLx);
        VLy = fmaf( w, dx, VLy);
        // AL_j = AL_{j-1} + alpha_{j-1}*(-dy,dx) + qd_j*(VLy_j, -VLx_j)
        ALx = fmaf(-alpha, dy, ALx); ALx = fmaf( qdj, VLy, ALx);
        ALy = fmaf( alpha, dx, ALy); ALy = fmaf(-qdj, VLx, ALy);
        w += qdj; alpha += qddj;
        // phi_j via angle addition
        float cn = cp*cq - sp*sq;
        float sn = sp*cq + cp*sq;
        cp = cn; sp = sn;
        lC[j*LSTR+tid] = cn; lS[j*LSTR+tid] = sn;
    }

    // ---- Backward scan, world frame. Carry GL=F_world, GA=N-moment accum.
    float GLx=0.f, GLy=0.f, GLz=0.f, GAx=0.f, GAy=0.f, GAz=0.f;
    float c = cp, s = sp;            // cos/sin phi_31 already in regs

    #pragma unroll
    for (int j = NJ-1; j >= 0; --j) {
        const float* pr = pre + 12*j;                  // uniform -> s_load
        float mcx=pr[0], mcy=pr[1], mcz=pr[2];
        float i2x=pr[3], i2y=pr[4], i2z=pr[5];
        float m=pr[6], mg=pr[7];
        float px=pr[8], py=pr[9], pz=pr[10], damp=pr[11];
        float qdj  = lQd [j*LSTR+tid];
        float qddj = lQdd[j*LSTR+tid];

        // Rotate the two constant vectors into world frame (z comps invariant).
        float mcwx = c*mcx - s*mcy;
        float mcwy = s*mcx + c*mcy;
        float iwx  = c*i2x - s*i2y;
        float iwy  = s*i2x + c*i2y;

        // fa_l = m*AL + mc x (0,0,alpha)         AL=(ALx,ALy,G)
        float fa_lx = m*ALx + mcwy*alpha;
        float fa_ly = m*ALy - mcwx*alpha;
        // fa_a = alpha*ibc2 + mc x AL
        float fa_ax = alpha*iwx + mcwy*GRAVZ - mcz*ALy;
        float fa_ay = alpha*iwy + mcz*ALx - mcwx*GRAVZ;
        float fa_az = alpha*i2z + mcwx*ALy - mcwy*ALx;
        // fv_l = m*VL + mc x (0,0,w)             VL=(VLx,VLy,0), z comp = 0
        float fv_lx = m*VLx + w*mcwy;
        float fv_ly = m*VLy - w*mcwx;
        // fv_a (x,y) = w*ibc2 + mc x VL
        float fv_ax = w*iwx - mcz*VLy;
        float fv_ay = w*iwy + mcz*VLx;
        // F = fa_l + (0,0,w) x fv_l + GL ; Fz: cf_lz=0, fa_lz=m*G
        float Fx = fa_lx - w*fv_ly + GLx;
        float Fy = fa_ly + w*fv_lx + GLy;
        float Fz = mg + GLz;
        // N = fa_a + (0,0,w) x fv_a + VL x fv_l + GA
        // VL x fv_l = (0,0, VLx*fv_ly - VLy*fv_lx)  (both z comps zero)
        float Nx = fa_ax - w*fv_ay + GAx;
        float Ny = fa_ay + w*fv_ax + GAy;
        float Nz = fa_az + (VLx*fv_ly - VLy*fv_lx) + GAz;

        lQdd[j*LSTR+tid] = Nz + damp*qdj;              // tau (dead qdd slot)

        if (j > 0) {
            float cpp = lC[(j-1)*LSTR+tid];            // cos/sin phi_{j-1}
            float spp = lS[(j-1)*LSTR+tid];
            float dx = cpp*px - spp*py;
            float dy = spp*px + cpp*py;
            // GA' = N + d x F, d=(dx,dy,pz); GL' = F
            GAx = Nx + dy*Fz - pz*Fy;
            GAy = Ny + pz*Fx - dx*Fz;
            GAz = Nz + dx*Fy - dy*Fx;
            GLx = Fx; GLy = Fy; GLz = Fz;
            // Down-step state to joint j-1 (world inversion, trivial):
            w -= qdj; alpha -= qddj;
            float nVLx = fmaf( w, dy, VLx);
            float nVLy = fmaf(-w, dx, VLy);
            ALx = fmaf( alpha, dy, ALx); ALx = fmaf(-qdj, VLy, ALx);
            ALy = fmaf(-alpha, dx, ALy); ALy = fmaf( qdj, VLx, ALy);
            VLx = nVLx; VLy = nVLy;
            c = cpp; s = spp;
        }
    }
    __syncthreads();

    // ---- Transposed coalesced float4 output store.
    float4* o4 = reinterpret_cast<float4*>(out);
    #pragma unroll
    for (int i = 0; i < NJ/4; ++i) {
        int lin = i*BLK + tid;
        size_t g = blk4 + lin;
        if (g <= maxIdx4) {
            int row  = lin >> 3;
            int col4 = (lin & 7) * 4;
            float4 v;
            v.x = lQdd[(col4+0)*LSTR+row];
            v.y = lQdd[(col4+1)*LSTR+row];
            v.z = lQdd[(col4+2)*LSTR+row];
            v.w = lQdd[(col4+3)*LSTR+row];
            o4[g] = v;
        }
    }
}

extern "C" void kernel_launch(void* const* d_in, const int* in_sizes, int n_in,
                              void* d_out, int out_size, void* d_ws, size_t ws_size,
                              hipStream_t stream) {
    const float* q       = (const float*)d_in[0];
    const float* qd      = (const float*)d_in[1];
    const float* qdd     = (const float*)d_in[2];
    const float* trans   = (const float*)d_in[3];
    const float* mass    = (const float*)d_in[4];
    const float* com     = (const float*)d_in[5];
    const float* inertia = (const float*)d_in[6];
    const float* damping = (const float*)d_in[7];
    float* out = (float*)d_out;
    float* pre = (float*)d_ws;   // 32*12 floats = 1536 B

    hipLaunchKernelGGL(precomp_kernel, dim3(1), dim3(64), 0, stream,
                       mass, com, inertia, trans, damping, pre);

    int Bn = in_sizes[0] / NJ;
    int grid = (Bn + BLK - 1) / BLK;
    hipLaunchKernelGGL(rnea_kernel, dim3(grid), dim3(BLK), 0, stream,
                       q, qd, qdd, pre, out, Bn);
}